// Round 8
// baseline (834.919 us; speedup 1.0000x reference)
//
#include <hip/hip_runtime.h>
#include <cstddef>

#define T_SEQ 11
#define STEPS 80

typedef _Float16 f16;
typedef _Float16 f16x4 __attribute__((ext_vector_type(4)));
typedef _Float16 f16x8 __attribute__((ext_vector_type(8)));
typedef float    f32x4 __attribute__((ext_vector_type(4)));

__device__ __forceinline__ f32x4 mfma16(f16x8 a, f16x8 b, f32x4 c) {
    return __builtin_amdgcn_mfma_f32_16x16x32_f16(a, b, c, 0, 0, 0);
}
__device__ __forceinline__ float sig1(float x) {
    return __fdividef(1.f, 1.f + __expf(-x));
}
__device__ __forceinline__ float th1(float x) {
    return 1.f - __fdividef(2.f, __expf(2.f * x) + 1.f);
}

// A-frag: lane holds W[row][k0..k0+7] (m = lane&15 selects row within tile).
__device__ __forceinline__ f16x8 wfrag(const float* __restrict__ W, int row, int k0) {
    f16x8 r;
    #pragma unroll
    for (int i = 0; i < 8; ++i) r[i] = (f16)W[row * 64 + k0 + i];
    return r;
}
// Composed decoder-l0 gi weights: Wcomb[g][k] = Wih0[g][0]*fcW[0][k] + Wih0[g][1]*fcW[1][k]
__device__ __forceinline__ f16x8 cfrag(const float* __restrict__ Wih0,
                                       const float* __restrict__ fcW, int row, int k0) {
    f16x8 r;
    #pragma unroll
    for (int i = 0; i < 8; ++i)
        r[i] = (f16)(Wih0[row * 2] * fcW[k0 + i] + Wih0[row * 2 + 1] * fcW[64 + k0 + i]);
    return r;
}

struct WSet {
    f16x8 xR[2], xZ[2], xN[2];   // gi-source weights (MFMA path)
    f16x8 hR[2], hZ[2], hN[2];   // recurrent weights
    f32x4 bR, bZ, bNi, bNh;      // biases, vector over rg (j = j4+rg)
};

__device__ __forceinline__ void load_h_side(WSet& W,
    const float* __restrict__ Whh, const float* __restrict__ bih,
    const float* __restrict__ bhh, int jA, int j4, int quad)
{
    #pragma unroll
    for (int ks = 0; ks < 2; ++ks) {
        const int k0 = ks * 32 + quad * 8;
        W.hR[ks] = wfrag(Whh, jA,       k0);
        W.hZ[ks] = wfrag(Whh, jA + 64,  k0);
        W.hN[ks] = wfrag(Whh, jA + 128, k0);
    }
    #pragma unroll
    for (int rg = 0; rg < 4; ++rg) {
        W.bR[rg]  = bih[j4 + rg] + bhh[j4 + rg];
        W.bZ[rg]  = bih[64 + j4 + rg] + bhh[64 + j4 + rg];
        W.bNi[rg] = bih[128 + j4 + rg];
        W.bNh[rg] = bhh[128 + j4 + rg];
    }
}
__device__ __forceinline__ void load_x_side(WSet& W, const float* __restrict__ Wx,
                                            int jA, int quad)
{
    #pragma unroll
    for (int ks = 0; ks < 2; ++ks) {
        const int k0 = ks * 32 + quad * 8;
        W.xR[ks] = wfrag(Wx, jA,       k0);
        W.xZ[ks] = wfrag(Wx, jA + 64,  k0);
        W.xN[ks] = wfrag(Wx, jA + 128, k0);
    }
}

// One GRU cell, D[j][row] orientation. h lives ONLY as f16 in the swizzled
// LDS buffers: h_old is read back from the current buffer at the same slot
// (wo+mo) this thread will write in Dst (1 ds_read_b64). This removes the
// fp32 master that round 5 spilled to scratch (49MB) and round 7 kept in
// 32KB LDS while STILL spilling ~15 regs (WRITE 35.9 vs 20.5 MB ideal).
// Accuracy cost: one extra f16 rounding on the z*(ho-n) path only - the
// matmul path already consumed h as f16.
template<bool XM>
__device__ __forceinline__ void cell(const WSet& W,
    const f16* __restrict__ Xs, const f16* __restrict__ Hs, f16* __restrict__ Dst,
    const f32x4* __restrict__ xw, const float2* __restrict__ xv,
    int ro0, int ro1, int wo)
{
    #pragma unroll
    for (int mt = 0; mt < 4; ++mt) {
        f32x4 aR = W.bR, aZ = W.bZ, aNi = W.bNi, aNh = W.bNh;
        const int mo = mt * 1024;
        f16x8 hb0 = *(const f16x8*)(Hs + ro0 + mo);
        f16x8 hb1 = *(const f16x8*)(Hs + ro1 + mo);
        f16x4 ho4 = *(const f16x4*)(Hs + wo + mo);   // h_old, issued early
        aR  = mfma16(W.hR[0], hb0, aR);  aR  = mfma16(W.hR[1], hb1, aR);
        aZ  = mfma16(W.hZ[0], hb0, aZ);  aZ  = mfma16(W.hZ[1], hb1, aZ);
        aNh = mfma16(W.hN[0], hb0, aNh); aNh = mfma16(W.hN[1], hb1, aNh);
        if constexpr (XM) {
            f16x8 xb0 = *(const f16x8*)(Xs + ro0 + mo);
            f16x8 xb1 = *(const f16x8*)(Xs + ro1 + mo);
            aR  = mfma16(W.xR[0], xb0, aR);  aR  = mfma16(W.xR[1], xb1, aR);
            aZ  = mfma16(W.xZ[0], xb0, aZ);  aZ  = mfma16(W.xZ[1], xb1, aZ);
            aNi = mfma16(W.xN[0], xb0, aNi); aNi = mfma16(W.xN[1], xb1, aNi);
        } else {
            const float x0 = xv[mt].x, x1 = xv[mt].y;
            aR  += x0 * xw[0] + x1 * xw[1];
            aZ  += x0 * xw[2] + x1 * xw[3];
            aNi += x0 * xw[4] + x1 * xw[5];
        }
        f16x4 o;
        #pragma unroll
        for (int i = 0; i < 4; ++i) {
            const float r = sig1(aR[i]);
            const float z = sig1(aZ[i]);
            const float n = th1(aNi[i] + r * aNh[i]);
            const float h = n + z * ((float)ho4[i] - n);
            o[i] = (f16)h;
        }
        *(f16x4*)(Dst + wo + mo) = o;   // one ds_write_b64, swizzle-aligned
    }
}

// (256,3): LDS is now 38.4KB -> 3 blocks/CU fit if regs <= ~170/wave.
// Post-hm-removal footprint ~160 unified regs. 12 waves/CU for a
// latency-bound recurrence.
__global__ __launch_bounds__(256, 3)
void gru_traj_mfma5(
    const float* __restrict__ x,
    const float* __restrict__ eWih0, const float* __restrict__ eWhh0,
    const float* __restrict__ ebih0, const float* __restrict__ ebhh0,
    const float* __restrict__ eWih1, const float* __restrict__ eWhh1,
    const float* __restrict__ ebih1, const float* __restrict__ ebhh1,
    const float* __restrict__ dWih0, const float* __restrict__ dWhh0,
    const float* __restrict__ dbih0, const float* __restrict__ dbhh0,
    const float* __restrict__ dWih1, const float* __restrict__ dWhh1,
    const float* __restrict__ dbih1, const float* __restrict__ dbhh1,
    const float* __restrict__ fcW,  const float* __restrict__ fcb,
    float* __restrict__ out)
{
    // 4 f16 h buffers (double-buffered per layer, MFMA operands), XOR-swizzled.
    __shared__ f16 hbuf[4][64 * 64];     // [0,1]=h0, [2,3]=h1   (32 KB)
    __shared__ float2 xe[T_SEQ * 64];    // [t][row] -> broadcast reads (5.5 KB)

    const int tid  = threadIdx.x;
    const int lane = tid & 63;
    const int w    = __builtin_amdgcn_readfirstlane(tid >> 6);
    const int quad = lane >> 4;
    const int col  = lane & 15;
    const int r0   = blockIdx.x * 64;

    for (int i = tid; i < T_SEQ * 64; i += 256) {
        const int t = i >> 6, r = i & 63;
        xe[i] = ((const float2*)x)[(size_t)(r0 + r) * T_SEQ + t];
    }
    for (int i = tid; i < 64 * 64; i += 256) { hbuf[0][i] = (f16)0.f; hbuf[2][i] = (f16)0.f; }

    // Swizzled offsets (halves): phys(row,k) = row*64 + (((k>>3)^(row&7))<<3) + (k&7)
    const int c7  = col & 7;
    const int ro0 = col * 64 + ((quad ^ c7) << 3);             // B-frag read, ks=0
    const int ro1 = col * 64 + (((4 + quad) ^ c7) << 3);       // B-frag read, ks=1
    const int wo  = col * 64 + ((((w << 1) | (quad >> 1)) ^ c7) << 3) + ((quad & 1) << 2);

    const int jA = w * 16 + col;        // A-frag W-row base (m = col)
    const int j4 = w * 16 + quad * 4;   // epilogue/bias j base (m = quad*4+rg)

    WSet W0, W1;
    load_h_side(W0, eWhh0, ebih0, ebhh0, jA, j4, quad);
    load_h_side(W1, eWhh1, ebih1, ebhh1, jA, j4, quad);
    load_x_side(W1, eWih1, jA, quad);
    {
        f32x4 xw[6];
        #pragma unroll
        for (int rg = 0; rg < 4; ++rg) {
            xw[0][rg] = eWih0[(j4 + rg) * 2];        xw[1][rg] = eWih0[(j4 + rg) * 2 + 1];
            xw[2][rg] = eWih0[(64 + j4 + rg) * 2];   xw[3][rg] = eWih0[(64 + j4 + rg) * 2 + 1];
            xw[4][rg] = eWih0[(128 + j4 + rg) * 2];  xw[5][rg] = eWih0[(128 + j4 + rg) * 2 + 1];
        }
        int c0 = 0, c1 = 0;
        __syncthreads();

        // ---------------- encoder: 1 barrier per pair ----------------
        #pragma unroll 1
        for (int t = 0; t < T_SEQ; ++t) {
            float2 xv[4];
            #pragma unroll
            for (int mt = 0; mt < 4; ++mt) xv[mt] = xe[t * 64 + mt * 16 + col];
            cell<false>(W0, hbuf[0], hbuf[c0], hbuf[c0 ^ 1], xw, xv, ro0, ro1, wo);
            c0 ^= 1; __syncthreads();
            cell<true>(W1, hbuf[c0], hbuf[2 + c1], hbuf[2 + (c1 ^ 1)], nullptr, nullptr, ro0, ro1, wo);
            c1 ^= 1;
        }
    }
    // encoder ran odd T_SEQ=11 -> c0=1, c1=1 now
    int c0 = 1, c1 = 1;

    // ---------------- phase switch ----------------
    load_h_side(W0, dWhh0, dbih0, dbhh0, jA, j4, quad);
    #pragma unroll
    for (int ks = 0; ks < 2; ++ks) {
        const int k0 = ks * 32 + quad * 8;
        W0.xR[ks] = cfrag(dWih0, fcW, jA,       k0);
        W0.xZ[ks] = cfrag(dWih0, fcW, jA + 64,  k0);
        W0.xN[ks] = cfrag(dWih0, fcW, jA + 128, k0);
    }
    #pragma unroll
    for (int rg = 0; rg < 4; ++rg) {   // fold fc_b through Wih0 into gi biases
        const int j = j4 + rg;
        W0.bR[rg]  += dWih0[j * 2] * fcb[0]         + dWih0[j * 2 + 1] * fcb[1];
        W0.bZ[rg]  += dWih0[(64 + j) * 2] * fcb[0]  + dWih0[(64 + j) * 2 + 1] * fcb[1];
        W0.bNi[rg] += dWih0[(128 + j) * 2] * fcb[0] + dWih0[(128 + j) * 2 + 1] * fcb[1];
    }
    load_h_side(W1, dWhh1, dbih1, dbhh1, jA, j4, quad);
    load_x_side(W1, dWih1, jA, quad);
    f16x8 fcf[2];
    #pragma unroll
    for (int ks = 0; ks < 2; ++ks) {
        #pragma unroll
        for (int i = 0; i < 8; ++i) fcf[ks][i] = (f16)0.f;
        if (col < 2) fcf[ks] = wfrag(fcW, col, ks * 32 + quad * 8);
    }
    f32x4 pb;
    #pragma unroll
    for (int rg = 0; rg < 4; ++rg) pb[rg] = (quad == 0 && rg < 2) ? fcb[rg] : 0.f;

    float* __restrict__ outp = out + (size_t)r0 * (STEPS * 2);

    // ---------------- decoder step 0 (peeled: kills xw/xv live ranges) ----------------
    {
        f32x4 xw[6];
        #pragma unroll
        for (int rg = 0; rg < 4; ++rg) {   // x-path weights for decoder step 0 only
            xw[0][rg] = dWih0[(j4 + rg) * 2];        xw[1][rg] = dWih0[(j4 + rg) * 2 + 1];
            xw[2][rg] = dWih0[(64 + j4 + rg) * 2];   xw[3][rg] = dWih0[(64 + j4 + rg) * 2 + 1];
            xw[4][rg] = dWih0[(128 + j4 + rg) * 2];  xw[5][rg] = dWih0[(128 + j4 + rg) * 2 + 1];
        }
        float2 xv0[4];
        #pragma unroll
        for (int mt = 0; mt < 4; ++mt) xv0[mt] = xe[(T_SEQ - 1) * 64 + mt * 16 + col];
        cell<false>(W0, hbuf[0], hbuf[c0], hbuf[c0 ^ 1], xw, xv0, ro0, ro1, wo);
        c0 ^= 1; __syncthreads();
        cell<true>(W1, hbuf[c0], hbuf[2 + c1], hbuf[2 + (c1 ^ 1)], nullptr, nullptr, ro0, ro1, wo);
        c1 ^= 1; __syncthreads();
        f16x8 hb0 = *(const f16x8*)(hbuf[2 + c1] + ro0 + w * 1024);
        f16x8 hb1 = *(const f16x8*)(hbuf[2 + c1] + ro1 + w * 1024);
        f32x4 p = pb;
        p = mfma16(fcf[0], hb0, p);
        p = mfma16(fcf[1], hb1, p);
        if (quad == 0)
            *(float2*)&outp[(size_t)(w * 16 + col) * (STEPS * 2)] = make_float2(p[0], p[1]);
    }

    // ---------------- decoder steps 1..79: uniform body, 2 barriers ----------------
    #pragma unroll 1
    for (int s = 1; s < STEPS; ++s) {
        cell<true>(W0, hbuf[2 + c1], hbuf[c0], hbuf[c0 ^ 1], nullptr, nullptr, ro0, ro1, wo);
        c0 ^= 1; __syncthreads();
        cell<true>(W1, hbuf[c0], hbuf[2 + c1], hbuf[2 + (c1 ^ 1)], nullptr, nullptr, ro0, ro1, wo);
        c1 ^= 1; __syncthreads();

        // FC head on the fresh h1 (wave w covers rows 16w..16w+15)
        f16x8 hb0 = *(const f16x8*)(hbuf[2 + c1] + ro0 + w * 1024);
        f16x8 hb1 = *(const f16x8*)(hbuf[2 + c1] + ro1 + w * 1024);
        f32x4 p = pb;
        p = mfma16(fcf[0], hb0, p);
        p = mfma16(fcf[1], hb1, p);
        if (quad == 0) {
            *(float2*)&outp[(size_t)(w * 16 + col) * (STEPS * 2) + s * 2] =
                make_float2(p[0], p[1]);
        }
    }
}

extern "C" void kernel_launch(void* const* d_in, const int* in_sizes, int n_in,
                              void* d_out, int out_size, void* d_ws, size_t ws_size,
                              hipStream_t stream) {
    (void)n_in; (void)out_size; (void)d_ws; (void)ws_size;

    const float* x     = (const float*)d_in[0];
    const float* eWih0 = (const float*)d_in[1];
    const float* eWhh0 = (const float*)d_in[2];
    const float* ebih0 = (const float*)d_in[3];
    const float* ebhh0 = (const float*)d_in[4];
    const float* eWih1 = (const float*)d_in[5];
    const float* eWhh1 = (const float*)d_in[6];
    const float* ebih1 = (const float*)d_in[7];
    const float* ebhh1 = (const float*)d_in[8];
    const float* dWih0 = (const float*)d_in[9];
    const float* dWhh0 = (const float*)d_in[10];
    const float* dbih0 = (const float*)d_in[11];
    const float* dbhh0 = (const float*)d_in[12];
    const float* dWih1 = (const float*)d_in[13];
    const float* dWhh1 = (const float*)d_in[14];
    const float* dbih1 = (const float*)d_in[15];
    const float* dbhh1 = (const float*)d_in[16];
    const float* fcW   = (const float*)d_in[17];
    const float* fcb   = (const float*)d_in[18];
    float* out = (float*)d_out;

    const int b = in_sizes[0] / (T_SEQ * 2);   // 32768
    dim3 grid(b / 64), block(256);
    hipLaunchKernelGGL(gru_traj_mfma5, grid, block, 0, stream,
        x, eWih0, eWhh0, ebih0, ebhh0, eWih1, eWhh1, ebih1, ebhh1,
        dWih0, dWhh0, dbih0, dbhh0, dWih1, dWhh1, dbih1, dbhh1,
        fcW, fcb, out);
}

// Round 9
// 773.089 us; speedup vs baseline: 1.0800x; 1.0800x over previous
//
#include <hip/hip_runtime.h>
#include <cstddef>

#define T_SEQ 11
#define STEPS 80

typedef _Float16 f16;
typedef _Float16 f16x4 __attribute__((ext_vector_type(4)));
typedef _Float16 f16x8 __attribute__((ext_vector_type(8)));
typedef float    f32x4 __attribute__((ext_vector_type(4)));

__device__ __forceinline__ f32x4 mfma16(f16x8 a, f16x8 b, f32x4 c) {
    return __builtin_amdgcn_mfma_f32_16x16x32_f16(a, b, c, 0, 0, 0);
}
__device__ __forceinline__ float sig1(float x) {
    return __fdividef(1.f, 1.f + __expf(-x));
}
__device__ __forceinline__ float th1(float x) {
    return 1.f - __fdividef(2.f, __expf(2.f * x) + 1.f);
}

// A-frag: lane holds W[row][k0..k0+7] (m = lane&15 selects row within tile).
__device__ __forceinline__ f16x8 wfrag(const float* __restrict__ W, int row, int k0) {
    f16x8 r;
    #pragma unroll
    for (int i = 0; i < 8; ++i) r[i] = (f16)W[row * 64 + k0 + i];
    return r;
}
// Composed decoder-l0 gi weights: Wcomb[g][k] = Wih0[g][0]*fcW[0][k] + Wih0[g][1]*fcW[1][k]
__device__ __forceinline__ f16x8 cfrag(const float* __restrict__ Wih0,
                                       const float* __restrict__ fcW, int row, int k0) {
    f16x8 r;
    #pragma unroll
    for (int i = 0; i < 8; ++i)
        r[i] = (f16)(Wih0[row * 2] * fcW[k0 + i] + Wih0[row * 2 + 1] * fcW[64 + k0 + i]);
    return r;
}

struct WSet {
    f16x8 xR[2], xZ[2], xN[2];   // gi-source weights (MFMA path)
    f16x8 hR[2], hZ[2], hN[2];   // recurrent weights
    f32x4 bR, bZ, bNi, bNh;      // biases, vector over rg (j = j4+rg)
};

__device__ __forceinline__ void load_h_side(WSet& W,
    const float* __restrict__ Whh, const float* __restrict__ bih,
    const float* __restrict__ bhh, int jA, int j4, int quad)
{
    #pragma unroll
    for (int ks = 0; ks < 2; ++ks) {
        const int k0 = ks * 32 + quad * 8;
        W.hR[ks] = wfrag(Whh, jA,       k0);
        W.hZ[ks] = wfrag(Whh, jA + 64,  k0);
        W.hN[ks] = wfrag(Whh, jA + 128, k0);
    }
    #pragma unroll
    for (int rg = 0; rg < 4; ++rg) {
        W.bR[rg]  = bih[j4 + rg] + bhh[j4 + rg];
        W.bZ[rg]  = bih[64 + j4 + rg] + bhh[64 + j4 + rg];
        W.bNi[rg] = bih[128 + j4 + rg];
        W.bNh[rg] = bhh[128 + j4 + rg];
    }
}
__device__ __forceinline__ void load_x_side(WSet& W, const float* __restrict__ Wx,
                                            int jA, int quad)
{
    #pragma unroll
    for (int ks = 0; ks < 2; ++ks) {
        const int k0 = ks * 32 + quad * 8;
        W.xR[ks] = wfrag(Wx, jA,       k0);
        W.xZ[ks] = wfrag(Wx, jA + 64,  k0);
        W.xN[ks] = wfrag(Wx, jA + 128, k0);
    }
}

// One GRU cell, D[j][row] orientation. h_old lives in per-thread registers
// (f16x4 ho[4], 4 VGPRs/layer): the slot this thread would read back as
// h_old is the exact slot it wrote last cell of this layer, so no LDS
// readback (round 8's ho4 ds_read doubled bank conflicts) and no fp32
// master (rounds 5-7: 32 VGPRs -> chronic scratch spill).
template<bool XM>
__device__ __forceinline__ void cell(const WSet& W,
    const f16* __restrict__ Xs, const f16* __restrict__ Hs, f16* __restrict__ Dst,
    f16x4 (&ho)[4],
    const f32x4* __restrict__ xw, const float2* __restrict__ xv,
    int ro0, int ro1, int wo)
{
    #pragma unroll
    for (int mt = 0; mt < 4; ++mt) {
        f32x4 aR = W.bR, aZ = W.bZ, aNi = W.bNi, aNh = W.bNh;
        const int mo = mt * 1024;
        f16x8 hb0 = *(const f16x8*)(Hs + ro0 + mo);
        f16x8 hb1 = *(const f16x8*)(Hs + ro1 + mo);
        aR  = mfma16(W.hR[0], hb0, aR);  aR  = mfma16(W.hR[1], hb1, aR);
        aZ  = mfma16(W.hZ[0], hb0, aZ);  aZ  = mfma16(W.hZ[1], hb1, aZ);
        aNh = mfma16(W.hN[0], hb0, aNh); aNh = mfma16(W.hN[1], hb1, aNh);
        if constexpr (XM) {
            f16x8 xb0 = *(const f16x8*)(Xs + ro0 + mo);
            f16x8 xb1 = *(const f16x8*)(Xs + ro1 + mo);
            aR  = mfma16(W.xR[0], xb0, aR);  aR  = mfma16(W.xR[1], xb1, aR);
            aZ  = mfma16(W.xZ[0], xb0, aZ);  aZ  = mfma16(W.xZ[1], xb1, aZ);
            aNi = mfma16(W.xN[0], xb0, aNi); aNi = mfma16(W.xN[1], xb1, aNi);
        } else {
            const float x0 = xv[mt].x, x1 = xv[mt].y;
            aR  += x0 * xw[0] + x1 * xw[1];
            aZ  += x0 * xw[2] + x1 * xw[3];
            aNi += x0 * xw[4] + x1 * xw[5];
        }
        f16x4 o;
        #pragma unroll
        for (int i = 0; i < 4; ++i) {
            const float r = sig1(aR[i]);
            const float z = sig1(aZ[i]);
            const float n = th1(aNi[i] + r * aNh[i]);
            const float h = n + z * ((float)ho[mt][i] - n);
            o[i] = (f16)h;
        }
        ho[mt] = o;
        *(f16x4*)(Dst + wo + mo) = o;   // one ds_write_b64, swizzle-aligned
    }
}

__global__ __launch_bounds__(256, 2)
void gru_traj_mfma6(
    const float* __restrict__ x,
    const float* __restrict__ eWih0, const float* __restrict__ eWhh0,
    const float* __restrict__ ebih0, const float* __restrict__ ebhh0,
    const float* __restrict__ eWih1, const float* __restrict__ eWhh1,
    const float* __restrict__ ebih1, const float* __restrict__ ebhh1,
    const float* __restrict__ dWih0, const float* __restrict__ dWhh0,
    const float* __restrict__ dbih0, const float* __restrict__ dbhh0,
    const float* __restrict__ dWih1, const float* __restrict__ dWhh1,
    const float* __restrict__ dbih1, const float* __restrict__ dbhh1,
    const float* __restrict__ fcW,  const float* __restrict__ fcb,
    float* __restrict__ out)
{
    // 4 f16 h buffers (double-buffered per layer, MFMA operands), XOR-swizzled.
    __shared__ f16 hbuf[4][64 * 64];     // [0,1]=h0, [2,3]=h1   (32 KB)
    __shared__ float2 xe[T_SEQ * 64];    // [t][row] -> broadcast reads (5.5 KB)

    const int tid  = threadIdx.x;
    const int lane = tid & 63;
    const int w    = __builtin_amdgcn_readfirstlane(tid >> 6);
    const int quad = lane >> 4;
    const int col  = lane & 15;
    const int r0   = blockIdx.x * 64;

    for (int i = tid; i < T_SEQ * 64; i += 256) {
        const int t = i >> 6, r = i & 63;
        xe[i] = ((const float2*)x)[(size_t)(r0 + r) * T_SEQ + t];
    }
    for (int i = tid; i < 64 * 64; i += 256) { hbuf[0][i] = (f16)0.f; hbuf[2][i] = (f16)0.f; }

    // Swizzled offsets (halves): phys(row,k) = row*64 + (((k>>3)^(row&7))<<3) + (k&7)
    const int c7  = col & 7;
    const int ro0 = col * 64 + ((quad ^ c7) << 3);             // B-frag read, ks=0
    const int ro1 = col * 64 + (((4 + quad) ^ c7) << 3);       // B-frag read, ks=1
    const int wo  = col * 64 + ((((w << 1) | (quad >> 1)) ^ c7) << 3) + ((quad & 1) << 2);

    const int jA = w * 16 + col;        // A-frag W-row base (m = col)
    const int j4 = w * 16 + quad * 4;   // epilogue/bias j base (m = quad*4+rg)

    f16x4 ho0[4], ho1[4];
    #pragma unroll
    for (int mt = 0; mt < 4; ++mt) {
        #pragma unroll
        for (int i = 0; i < 4; ++i) { ho0[mt][i] = (f16)0.f; ho1[mt][i] = (f16)0.f; }
    }

    WSet W0, W1;
    load_h_side(W0, eWhh0, ebih0, ebhh0, jA, j4, quad);
    load_h_side(W1, eWhh1, ebih1, ebhh1, jA, j4, quad);
    load_x_side(W1, eWih1, jA, quad);
    {
        f32x4 xw[6];
        #pragma unroll
        for (int rg = 0; rg < 4; ++rg) {
            xw[0][rg] = eWih0[(j4 + rg) * 2];        xw[1][rg] = eWih0[(j4 + rg) * 2 + 1];
            xw[2][rg] = eWih0[(64 + j4 + rg) * 2];   xw[3][rg] = eWih0[(64 + j4 + rg) * 2 + 1];
            xw[4][rg] = eWih0[(128 + j4 + rg) * 2];  xw[5][rg] = eWih0[(128 + j4 + rg) * 2 + 1];
        }
        int c0 = 0, c1 = 0;
        __syncthreads();

        // ---------------- encoder: 1 barrier per pair ----------------
        #pragma unroll 1
        for (int t = 0; t < T_SEQ; ++t) {
            float2 xv[4];
            #pragma unroll
            for (int mt = 0; mt < 4; ++mt) xv[mt] = xe[t * 64 + mt * 16 + col];
            cell<false>(W0, hbuf[0], hbuf[c0], hbuf[c0 ^ 1], ho0, xw, xv, ro0, ro1, wo);
            c0 ^= 1; __syncthreads();
            cell<true>(W1, hbuf[c0], hbuf[2 + c1], hbuf[2 + (c1 ^ 1)], ho1, nullptr, nullptr, ro0, ro1, wo);
            c1 ^= 1;
        }
    }
    // encoder ran odd T_SEQ=11 -> c0=1, c1=1 now
    int c0 = 1, c1 = 1;

    // ---------------- phase switch ----------------
    load_h_side(W0, dWhh0, dbih0, dbhh0, jA, j4, quad);
    #pragma unroll
    for (int ks = 0; ks < 2; ++ks) {
        const int k0 = ks * 32 + quad * 8;
        W0.xR[ks] = cfrag(dWih0, fcW, jA,       k0);
        W0.xZ[ks] = cfrag(dWih0, fcW, jA + 64,  k0);
        W0.xN[ks] = cfrag(dWih0, fcW, jA + 128, k0);
    }
    #pragma unroll
    for (int rg = 0; rg < 4; ++rg) {   // fold fc_b through Wih0 into gi biases
        const int j = j4 + rg;
        W0.bR[rg]  += dWih0[j * 2] * fcb[0]         + dWih0[j * 2 + 1] * fcb[1];
        W0.bZ[rg]  += dWih0[(64 + j) * 2] * fcb[0]  + dWih0[(64 + j) * 2 + 1] * fcb[1];
        W0.bNi[rg] += dWih0[(128 + j) * 2] * fcb[0] + dWih0[(128 + j) * 2 + 1] * fcb[1];
    }
    load_h_side(W1, dWhh1, dbih1, dbhh1, jA, j4, quad);
    load_x_side(W1, dWih1, jA, quad);
    f16x8 fcf[2];
    #pragma unroll
    for (int ks = 0; ks < 2; ++ks) {
        #pragma unroll
        for (int i = 0; i < 8; ++i) fcf[ks][i] = (f16)0.f;
        if (col < 2) fcf[ks] = wfrag(fcW, col, ks * 32 + quad * 8);
    }
    f32x4 pb;
    #pragma unroll
    for (int rg = 0; rg < 4; ++rg) pb[rg] = (quad == 0 && rg < 2) ? fcb[rg] : 0.f;

    float* __restrict__ outp = out + (size_t)r0 * (STEPS * 2);

    // ---------------- decoder step 0 (peeled: kills xw/xv live ranges) ----------------
    {
        f32x4 xw[6];
        #pragma unroll
        for (int rg = 0; rg < 4; ++rg) {   // x-path weights for decoder step 0 only
            xw[0][rg] = dWih0[(j4 + rg) * 2];        xw[1][rg] = dWih0[(j4 + rg) * 2 + 1];
            xw[2][rg] = dWih0[(64 + j4 + rg) * 2];   xw[3][rg] = dWih0[(64 + j4 + rg) * 2 + 1];
            xw[4][rg] = dWih0[(128 + j4 + rg) * 2];  xw[5][rg] = dWih0[(128 + j4 + rg) * 2 + 1];
        }
        float2 xv0[4];
        #pragma unroll
        for (int mt = 0; mt < 4; ++mt) xv0[mt] = xe[(T_SEQ - 1) * 64 + mt * 16 + col];
        cell<false>(W0, hbuf[0], hbuf[c0], hbuf[c0 ^ 1], ho0, xw, xv0, ro0, ro1, wo);
        c0 ^= 1; __syncthreads();
        cell<true>(W1, hbuf[c0], hbuf[2 + c1], hbuf[2 + (c1 ^ 1)], ho1, nullptr, nullptr, ro0, ro1, wo);
        c1 ^= 1; __syncthreads();
        f16x8 hb0 = *(const f16x8*)(hbuf[2 + c1] + ro0 + w * 1024);
        f16x8 hb1 = *(const f16x8*)(hbuf[2 + c1] + ro1 + w * 1024);
        f32x4 p = pb;
        p = mfma16(fcf[0], hb0, p);
        p = mfma16(fcf[1], hb1, p);
        if (quad == 0)
            *(float2*)&outp[(size_t)(w * 16 + col) * (STEPS * 2)] = make_float2(p[0], p[1]);
    }

    // ---------------- decoder steps 1..79: uniform body, 2 barriers ----------------
    #pragma unroll 1
    for (int s = 1; s < STEPS; ++s) {
        cell<true>(W0, hbuf[2 + c1], hbuf[c0], hbuf[c0 ^ 1], ho0, nullptr, nullptr, ro0, ro1, wo);
        c0 ^= 1; __syncthreads();
        cell<true>(W1, hbuf[c0], hbuf[2 + c1], hbuf[2 + (c1 ^ 1)], ho1, nullptr, nullptr, ro0, ro1, wo);
        c1 ^= 1; __syncthreads();

        // FC head on the fresh h1 (wave w covers rows 16w..16w+15)
        f16x8 hb0 = *(const f16x8*)(hbuf[2 + c1] + ro0 + w * 1024);
        f16x8 hb1 = *(const f16x8*)(hbuf[2 + c1] + ro1 + w * 1024);
        f32x4 p = pb;
        p = mfma16(fcf[0], hb0, p);
        p = mfma16(fcf[1], hb1, p);
        if (quad == 0) {
            *(float2*)&outp[(size_t)(w * 16 + col) * (STEPS * 2) + s * 2] =
                make_float2(p[0], p[1]);
        }
    }
}

extern "C" void kernel_launch(void* const* d_in, const int* in_sizes, int n_in,
                              void* d_out, int out_size, void* d_ws, size_t ws_size,
                              hipStream_t stream) {
    (void)n_in; (void)out_size; (void)d_ws; (void)ws_size;

    const float* x     = (const float*)d_in[0];
    const float* eWih0 = (const float*)d_in[1];
    const float* eWhh0 = (const float*)d_in[2];
    const float* ebih0 = (const float*)d_in[3];
    const float* ebhh0 = (const float*)d_in[4];
    const float* eWih1 = (const float*)d_in[5];
    const float* eWhh1 = (const float*)d_in[6];
    const float* ebih1 = (const float*)d_in[7];
    const float* ebhh1 = (const float*)d_in[8];
    const float* dWih0 = (const float*)d_in[9];
    const float* dWhh0 = (const float*)d_in[10];
    const float* dbih0 = (const float*)d_in[11];
    const float* dbhh0 = (const float*)d_in[12];
    const float* dWih1 = (const float*)d_in[13];
    const float* dWhh1 = (const float*)d_in[14];
    const float* dbih1 = (const float*)d_in[15];
    const float* dbhh1 = (const float*)d_in[16];
    const float* fcW   = (const float*)d_in[17];
    const float* fcb   = (const float*)d_in[18];
    float* out = (float*)d_out;

    const int b = in_sizes[0] / (T_SEQ * 2);   // 32768
    dim3 grid(b / 64), block(256);
    hipLaunchKernelGGL(gru_traj_mfma6, grid, block, 0, stream,
        x, eWih0, eWhh0, ebih0, ebhh0, eWih1, eWhh1, ebih1, ebhh1,
        dWih0, dWhh0, dbih0, dbhh0, dWih1, dWhh1, dbih1, dbhh1,
        fcW, fcb, out);
}

// Round 10
// 584.900 us; speedup vs baseline: 1.4275x; 1.3217x over previous
//
#include <hip/hip_runtime.h>
#include <cstddef>

#define T_SEQ 11
#define STEPS 80

typedef _Float16 f16;
typedef _Float16 f16x4 __attribute__((ext_vector_type(4)));
typedef _Float16 f16x8 __attribute__((ext_vector_type(8)));
typedef float    f32x4 __attribute__((ext_vector_type(4)));

// Gate prescale folded into weights/biases: sigmoid args x -log2(e), tanh
// (n-path) args x +2*log2(e) -> epilogue uses raw exp2/rcp, no per-gate muls.
#define SRC (-1.44269504f)
#define SNC ( 2.88539008f)

__device__ __forceinline__ f32x4 mfma16(f16x8 a, f16x8 b, f32x4 c) {
    return __builtin_amdgcn_mfma_f32_16x16x32_f16(a, b, c, 0, 0, 0);
}

// A-frag: lane holds sc*W[row][k0..k0+7].
__device__ __forceinline__ f16x8 wfrag(const float* __restrict__ W, int row, int k0, float sc) {
    f16x8 r;
    #pragma unroll
    for (int i = 0; i < 8; ++i) r[i] = (f16)(sc * W[row * 64 + k0 + i]);
    return r;
}
// Composed decoder-l0 gi weights: sc*(Wih0[g][0]*fcW[0][k] + Wih0[g][1]*fcW[1][k])
__device__ __forceinline__ f16x8 cfrag(const float* __restrict__ Wih0,
                                       const float* __restrict__ fcW, int row, int k0, float sc) {
    f16x8 r;
    #pragma unroll
    for (int i = 0; i < 8; ++i)
        r[i] = (f16)(sc * (Wih0[row * 2] * fcW[k0 + i] + Wih0[row * 2 + 1] * fcW[64 + k0 + i]));
    return r;
}

struct WSet {
    f16x8 xR[2], xZ[2], xN[2];   // gi-source weights (MFMA path)
    f16x8 hR[2], hZ[2], hN[2];   // recurrent weights
    f32x4 bR, bZ, bNi, bNh;      // prescaled biases (MFMA C-operand init)
};

__device__ __forceinline__ void load_h_side(WSet& W,
    const float* __restrict__ Whh, const float* __restrict__ bih,
    const float* __restrict__ bhh, int jA, int j4, int quad)
{
    #pragma unroll
    for (int ks = 0; ks < 2; ++ks) {
        const int k0 = ks * 32 + quad * 8;
        W.hR[ks] = wfrag(Whh, jA,       k0, SRC);
        W.hZ[ks] = wfrag(Whh, jA + 64,  k0, SRC);
        W.hN[ks] = wfrag(Whh, jA + 128, k0, SNC);
    }
    #pragma unroll
    for (int rg = 0; rg < 4; ++rg) {
        W.bR[rg]  = SRC * (bih[j4 + rg] + bhh[j4 + rg]);
        W.bZ[rg]  = SRC * (bih[64 + j4 + rg] + bhh[64 + j4 + rg]);
        W.bNi[rg] = SNC * bih[128 + j4 + rg];
        W.bNh[rg] = SNC * bhh[128 + j4 + rg];
    }
}
__device__ __forceinline__ void load_x_side(WSet& W, const float* __restrict__ Wx,
                                            int jA, int quad)
{
    #pragma unroll
    for (int ks = 0; ks < 2; ++ks) {
        const int k0 = ks * 32 + quad * 8;
        W.xR[ks] = wfrag(Wx, jA,       k0, SRC);
        W.xZ[ks] = wfrag(Wx, jA + 64,  k0, SRC);
        W.xN[ks] = wfrag(Wx, jA + 128, k0, SNC);
    }
}

// One GRU cell, D[j][row]. All LDS pointers must be compile-time offsets of
// the shared block (call sites use literal buffer indices) so ds ops get
// immediate offsets - round 9's runtime c0/c1 indices forced per-cell address
// recompute. Biases enter as the first MFMA's C operand (no acc-init movs).
template<bool XM>
__device__ __forceinline__ void cell(const WSet& W,
    const f16* __restrict__ Xs, const f16* __restrict__ Hs, f16* __restrict__ Dst,
    f16x4 (&ho)[4],
    const f32x4* __restrict__ xw, const float2* __restrict__ xv,
    int ro0, int ro1, int wo)
{
    #pragma unroll
    for (int mt = 0; mt < 4; ++mt) {
        const int mo = mt * 1024;
        f16x8 hb0 = *(const f16x8*)(Hs + ro0 + mo);
        f16x8 hb1 = *(const f16x8*)(Hs + ro1 + mo);
        f32x4 aR  = mfma16(W.hR[0], hb0, W.bR);
        f32x4 aZ  = mfma16(W.hZ[0], hb0, W.bZ);
        f32x4 aNh = mfma16(W.hN[0], hb0, W.bNh);
        aR  = mfma16(W.hR[1], hb1, aR);
        aZ  = mfma16(W.hZ[1], hb1, aZ);
        aNh = mfma16(W.hN[1], hb1, aNh);
        f32x4 aNi;
        if constexpr (XM) {
            f16x8 xb0 = *(const f16x8*)(Xs + ro0 + mo);
            f16x8 xb1 = *(const f16x8*)(Xs + ro1 + mo);
            aR  = mfma16(W.xR[0], xb0, aR);    aR  = mfma16(W.xR[1], xb1, aR);
            aZ  = mfma16(W.xZ[0], xb0, aZ);    aZ  = mfma16(W.xZ[1], xb1, aZ);
            aNi = mfma16(W.xN[0], xb0, W.bNi); aNi = mfma16(W.xN[1], xb1, aNi);
        } else {
            const float x0 = xv[mt].x, x1 = xv[mt].y;
            aR  += x0 * xw[0] + x1 * xw[1];
            aZ  += x0 * xw[2] + x1 * xw[3];
            aNi  = W.bNi + x0 * xw[4] + x1 * xw[5];
        }
        f16x4 o;
        #pragma unroll
        for (int i = 0; i < 4; ++i) {
            const float r = __builtin_amdgcn_rcpf(1.f + exp2f(aR[i]));
            const float z = __builtin_amdgcn_rcpf(1.f + exp2f(aZ[i]));
            const float n = 1.f - 2.f * __builtin_amdgcn_rcpf(1.f + exp2f(aNi[i] + r * aNh[i]));
            const float h = n + z * ((float)ho[mt][i] - n);
            o[i] = (f16)h;
        }
        ho[mt] = o;
        *(f16x4*)(Dst + wo + mo) = o;
    }
}

__global__ __launch_bounds__(256, 2)
void gru_traj_mfma7(
    const float* __restrict__ x,
    const float* __restrict__ eWih0, const float* __restrict__ eWhh0,
    const float* __restrict__ ebih0, const float* __restrict__ ebhh0,
    const float* __restrict__ eWih1, const float* __restrict__ eWhh1,
    const float* __restrict__ ebih1, const float* __restrict__ ebhh1,
    const float* __restrict__ dWih0, const float* __restrict__ dWhh0,
    const float* __restrict__ dbih0, const float* __restrict__ dbhh0,
    const float* __restrict__ dWih1, const float* __restrict__ dWhh1,
    const float* __restrict__ dbih1, const float* __restrict__ dbhh1,
    const float* __restrict__ fcW,  const float* __restrict__ fcb,
    float* __restrict__ out)
{
    // buffers: [0,1]=h0 double-buffer, [2,3]=h1 double-buffer, XOR-swizzled.
    __shared__ f16 hbuf[4][64 * 64];     // 32 KB
    __shared__ float2 xe[T_SEQ * 64];    // [t][row], 5.5 KB

    const int tid  = threadIdx.x;
    const int lane = tid & 63;
    const int w    = __builtin_amdgcn_readfirstlane(tid >> 6);
    const int quad = lane >> 4;
    const int col  = lane & 15;
    const int r0   = blockIdx.x * 64;

    // coalesced x staging: consecutive tid -> consecutive global float2
    {
        const float2* x2 = (const float2*)x;
        for (int i = tid; i < 64 * T_SEQ; i += 256) {
            const int row = i / T_SEQ, t = i - row * T_SEQ;
            xe[t * 64 + row] = x2[(size_t)r0 * T_SEQ + i];
        }
    }
    for (int i = tid; i < 64 * 64; i += 256) { hbuf[0][i] = (f16)0.f; hbuf[2][i] = (f16)0.f; }

    // Swizzle (halves): phys(row,k) = row*64 + (((k>>3)^(row&7))<<3) + (k&7)
    const int c7  = col & 7;
    const int ro0 = col * 64 + ((quad ^ c7) << 3);
    const int ro1 = col * 64 + (((4 + quad) ^ c7) << 3);
    const int wo  = col * 64 + ((((w << 1) | (quad >> 1)) ^ c7) << 3) + ((quad & 1) << 2);

    const int jA = w * 16 + col;
    const int j4 = w * 16 + quad * 4;

    f16x4 ho0[4], ho1[4];
    #pragma unroll
    for (int mt = 0; mt < 4; ++mt) {
        #pragma unroll
        for (int i = 0; i < 4; ++i) { ho0[mt][i] = (f16)0.f; ho1[mt][i] = (f16)0.f; }
    }

    WSet W0, W1;
    load_h_side(W0, eWhh0, ebih0, ebhh0, jA, j4, quad);
    load_h_side(W1, eWhh1, ebih1, ebhh1, jA, j4, quad);
    load_x_side(W1, eWih1, jA, quad);
    {
        f32x4 xw[6];
        #pragma unroll
        for (int rg = 0; rg < 4; ++rg) {
            xw[0][rg] = SRC * eWih0[(j4 + rg) * 2];        xw[1][rg] = SRC * eWih0[(j4 + rg) * 2 + 1];
            xw[2][rg] = SRC * eWih0[(64 + j4 + rg) * 2];   xw[3][rg] = SRC * eWih0[(64 + j4 + rg) * 2 + 1];
            xw[4][rg] = SNC * eWih0[(128 + j4 + rg) * 2];  xw[5][rg] = SNC * eWih0[(128 + j4 + rg) * 2 + 1];
        }
        __syncthreads();

        // ---------------- encoder: static buffers, 1 barrier/step ----------------
        // even t: l0 hbuf[0]->hbuf[1]; l1 X=hbuf[1], h=hbuf[2]->hbuf[3]
        // odd  t: l0 hbuf[1]->hbuf[0]; l1 X=hbuf[0], h=hbuf[3]->hbuf[2]
        #pragma unroll 1
        for (int t = 0; t < T_SEQ - 1; t += 2) {
            float2 xv[4];
            #pragma unroll
            for (int mt = 0; mt < 4; ++mt) xv[mt] = xe[t * 64 + mt * 16 + col];
            cell<false>(W0, hbuf[0], hbuf[0], hbuf[1], ho0, xw, xv, ro0, ro1, wo);
            __syncthreads();
            cell<true >(W1, hbuf[1], hbuf[2], hbuf[3], ho1, nullptr, nullptr, ro0, ro1, wo);
            #pragma unroll
            for (int mt = 0; mt < 4; ++mt) xv[mt] = xe[(t + 1) * 64 + mt * 16 + col];
            cell<false>(W0, hbuf[1], hbuf[1], hbuf[0], ho0, xw, xv, ro0, ro1, wo);
            __syncthreads();
            cell<true >(W1, hbuf[0], hbuf[3], hbuf[2], ho1, nullptr, nullptr, ro0, ro1, wo);
        }
        {   // t = 10 (even body)
            float2 xv[4];
            #pragma unroll
            for (int mt = 0; mt < 4; ++mt) xv[mt] = xe[10 * 64 + mt * 16 + col];
            cell<false>(W0, hbuf[0], hbuf[0], hbuf[1], ho0, xw, xv, ro0, ro1, wo);
            __syncthreads();
            cell<true >(W1, hbuf[1], hbuf[2], hbuf[3], ho1, nullptr, nullptr, ro0, ro1, wo);
        }
    }
    // now: h0 cur = hbuf[1], h1 cur = hbuf[3]

    // ---------------- phase switch ----------------
    load_h_side(W0, dWhh0, dbih0, dbhh0, jA, j4, quad);
    #pragma unroll
    for (int ks = 0; ks < 2; ++ks) {
        const int k0 = ks * 32 + quad * 8;
        W0.xR[ks] = cfrag(dWih0, fcW, jA,       k0, SRC);
        W0.xZ[ks] = cfrag(dWih0, fcW, jA + 64,  k0, SRC);
        W0.xN[ks] = cfrag(dWih0, fcW, jA + 128, k0, SNC);
    }
    #pragma unroll
    for (int rg = 0; rg < 4; ++rg) {   // fold fc_b through Wih0 (prescaled)
        const int j = j4 + rg;
        W0.bR[rg]  += SRC * (dWih0[j * 2] * fcb[0]         + dWih0[j * 2 + 1] * fcb[1]);
        W0.bZ[rg]  += SRC * (dWih0[(64 + j) * 2] * fcb[0]  + dWih0[(64 + j) * 2 + 1] * fcb[1]);
        W0.bNi[rg] += SNC * (dWih0[(128 + j) * 2] * fcb[0] + dWih0[(128 + j) * 2 + 1] * fcb[1]);
    }
    load_h_side(W1, dWhh1, dbih1, dbhh1, jA, j4, quad);
    load_x_side(W1, dWih1, jA, quad);
    f16x8 fcf[2];
    #pragma unroll
    for (int ks = 0; ks < 2; ++ks) {
        #pragma unroll
        for (int i = 0; i < 8; ++i) fcf[ks][i] = (f16)0.f;
        if (col < 2) fcf[ks] = wfrag(fcW, col, ks * 32 + quad * 8, 1.0f);
    }
    f32x4 pb;
    #pragma unroll
    for (int rg = 0; rg < 4; ++rg) pb[rg] = (quad == 0 && rg < 2) ? fcb[rg] : 0.f;

    float* __restrict__ op = out + (size_t)(r0 + w * 16 + col) * (STEPS * 2);

    // ---------------- decoder step 0 (peeled, x-path) ----------------
    {
        f32x4 xw[6];
        #pragma unroll
        for (int rg = 0; rg < 4; ++rg) {
            xw[0][rg] = SRC * dWih0[(j4 + rg) * 2];        xw[1][rg] = SRC * dWih0[(j4 + rg) * 2 + 1];
            xw[2][rg] = SRC * dWih0[(64 + j4 + rg) * 2];   xw[3][rg] = SRC * dWih0[(64 + j4 + rg) * 2 + 1];
            xw[4][rg] = SNC * dWih0[(128 + j4 + rg) * 2];  xw[5][rg] = SNC * dWih0[(128 + j4 + rg) * 2 + 1];
        }
        float2 xv0[4];
        #pragma unroll
        for (int mt = 0; mt < 4; ++mt) xv0[mt] = xe[10 * 64 + mt * 16 + col];
        cell<false>(W0, hbuf[1], hbuf[1], hbuf[0], ho0, xw, xv0, ro0, ro1, wo);
        __syncthreads();
        cell<true >(W1, hbuf[0], hbuf[3], hbuf[2], ho1, nullptr, nullptr, ro0, ro1, wo);
        __syncthreads();
        f16x8 hb0 = *(const f16x8*)(hbuf[2] + ro0 + w * 1024);
        f16x8 hb1 = *(const f16x8*)(hbuf[2] + ro1 + w * 1024);
        f32x4 p = mfma16(fcf[0], hb0, pb);
        p = mfma16(fcf[1], hb1, p);
        if (quad == 0) *(float2*)op = make_float2(p[0], p[1]);
        op += 2;
    }

    // ---------------- decoder: 39 pairs (odd, even) + 1 odd, static buffers ----
    #pragma unroll 1
    for (int sp = 0; sp < 39; ++sp) {
        // odd step: l0 X=hbuf[2], h=hbuf[0]->hbuf[1]; l1 X=hbuf[1], h=hbuf[2]->hbuf[3]
        cell<true>(W0, hbuf[2], hbuf[0], hbuf[1], ho0, nullptr, nullptr, ro0, ro1, wo);
        __syncthreads();
        cell<true>(W1, hbuf[1], hbuf[2], hbuf[3], ho1, nullptr, nullptr, ro0, ro1, wo);
        __syncthreads();
        {
            f16x8 hb0 = *(const f16x8*)(hbuf[3] + ro0 + w * 1024);
            f16x8 hb1 = *(const f16x8*)(hbuf[3] + ro1 + w * 1024);
            f32x4 p = mfma16(fcf[0], hb0, pb);
            p = mfma16(fcf[1], hb1, p);
            if (quad == 0) *(float2*)op = make_float2(p[0], p[1]);
            op += 2;
        }
        // even step: l0 X=hbuf[3], h=hbuf[1]->hbuf[0]; l1 X=hbuf[0], h=hbuf[3]->hbuf[2]
        cell<true>(W0, hbuf[3], hbuf[1], hbuf[0], ho0, nullptr, nullptr, ro0, ro1, wo);
        __syncthreads();
        cell<true>(W1, hbuf[0], hbuf[3], hbuf[2], ho1, nullptr, nullptr, ro0, ro1, wo);
        __syncthreads();
        {
            f16x8 hb0 = *(const f16x8*)(hbuf[2] + ro0 + w * 1024);
            f16x8 hb1 = *(const f16x8*)(hbuf[2] + ro1 + w * 1024);
            f32x4 p = mfma16(fcf[0], hb0, pb);
            p = mfma16(fcf[1], hb1, p);
            if (quad == 0) *(float2*)op = make_float2(p[0], p[1]);
            op += 2;
        }
    }
    {   // s = 79 (odd body)
        cell<true>(W0, hbuf[2], hbuf[0], hbuf[1], ho0, nullptr, nullptr, ro0, ro1, wo);
        __syncthreads();
        cell<true>(W1, hbuf[1], hbuf[2], hbuf[3], ho1, nullptr, nullptr, ro0, ro1, wo);
        __syncthreads();
        f16x8 hb0 = *(const f16x8*)(hbuf[3] + ro0 + w * 1024);
        f16x8 hb1 = *(const f16x8*)(hbuf[3] + ro1 + w * 1024);
        f32x4 p = mfma16(fcf[0], hb0, pb);
        p = mfma16(fcf[1], hb1, p);
        if (quad == 0) *(float2*)op = make_float2(p[0], p[1]);
    }
}

extern "C" void kernel_launch(void* const* d_in, const int* in_sizes, int n_in,
                              void* d_out, int out_size, void* d_ws, size_t ws_size,
                              hipStream_t stream) {
    (void)n_in; (void)out_size; (void)d_ws; (void)ws_size;

    const float* x     = (const float*)d_in[0];
    const float* eWih0 = (const float*)d_in[1];
    const float* eWhh0 = (const float*)d_in[2];
    const float* ebih0 = (const float*)d_in[3];
    const float* ebhh0 = (const float*)d_in[4];
    const float* eWih1 = (const float*)d_in[5];
    const float* eWhh1 = (const float*)d_in[6];
    const float* ebih1 = (const float*)d_in[7];
    const float* ebhh1 = (const float*)d_in[8];
    const float* dWih0 = (const float*)d_in[9];
    const float* dWhh0 = (const float*)d_in[10];
    const float* dbih0 = (const float*)d_in[11];
    const float* dbhh0 = (const float*)d_in[12];
    const float* dWih1 = (const float*)d_in[13];
    const float* dWhh1 = (const float*)d_in[14];
    const float* dbih1 = (const float*)d_in[15];
    const float* dbhh1 = (const float*)d_in[16];
    const float* fcW   = (const float*)d_in[17];
    const float* fcb   = (const float*)d_in[18];
    float* out = (float*)d_out;

    const int b = in_sizes[0] / (T_SEQ * 2);   // 32768
    dim3 grid(b / 64), block(256);
    hipLaunchKernelGGL(gru_traj_mfma7, grid, block, 0, stream,
        x, eWih0, eWhh0, ebih0, ebhh0, eWih1, eWhh1, ebih1, ebhh1,
        dWih0, dWhh0, dbih0, dbhh0, dWih1, dWhh1, dbih1, dbhh1,
        fcW, fcb, out);
}

// Round 11
// 456.366 us; speedup vs baseline: 1.8295x; 1.2816x over previous
//
#include <hip/hip_runtime.h>
#include <cstddef>

#define T_SEQ 11
#define STEPS 80

typedef _Float16 f16;
typedef _Float16 f16x4 __attribute__((ext_vector_type(4)));
typedef _Float16 f16x8 __attribute__((ext_vector_type(8)));
typedef float    f32x4 __attribute__((ext_vector_type(4)));

// Gate prescale folded into weights/biases: sigmoid args x -log2(e), tanh
// (n-path) args x +2*log2(e) -> epilogue uses raw exp2/rcp, no per-gate muls.
#define SRC (-1.44269504f)
#define SNC ( 2.88539008f)

__device__ __forceinline__ f32x4 mfma16(f16x8 a, f16x8 b, f32x4 c) {
    return __builtin_amdgcn_mfma_f32_16x16x32_f16(a, b, c, 0, 0, 0);
}
// Raw v_exp_f32: plain -O3 (no fast-math) lowers exp2f() through the OCML
// guarded sequence (denormal input scaling) - several extra VALU ops per
// call. Gate args are far from the guarded range; use the bare instruction.
__device__ __forceinline__ float exp2r(float x) { return __builtin_amdgcn_exp2f(x); }

// A-frag: lane holds sc*W[row][k0..k0+7].
__device__ __forceinline__ f16x8 wfrag(const float* __restrict__ W, int row, int k0, float sc) {
    f16x8 r;
    #pragma unroll
    for (int i = 0; i < 8; ++i) r[i] = (f16)(sc * W[row * 64 + k0 + i]);
    return r;
}
// Composed decoder-l0 gi weights: sc*(Wih0[g][0]*fcW[0][k] + Wih0[g][1]*fcW[1][k])
__device__ __forceinline__ f16x8 cfrag(const float* __restrict__ Wih0,
                                       const float* __restrict__ fcW, int row, int k0, float sc) {
    f16x8 r;
    #pragma unroll
    for (int i = 0; i < 8; ++i)
        r[i] = (f16)(sc * (Wih0[row * 2] * fcW[k0 + i] + Wih0[row * 2 + 1] * fcW[64 + k0 + i]));
    return r;
}

struct WSet {
    f16x8 xR[2], xZ[2], xN[2];   // gi-source weights (MFMA path)
    f16x8 hR[2], hZ[2], hN[2];   // recurrent weights
    f32x4 bR, bZ, bNi, bNh;      // prescaled biases (MFMA C-operand init)
};

__device__ __forceinline__ void load_h_side(WSet& W,
    const float* __restrict__ Whh, const float* __restrict__ bih,
    const float* __restrict__ bhh, int jA, int j4, int quad)
{
    #pragma unroll
    for (int ks = 0; ks < 2; ++ks) {
        const int k0 = ks * 32 + quad * 8;
        W.hR[ks] = wfrag(Whh, jA,       k0, SRC);
        W.hZ[ks] = wfrag(Whh, jA + 64,  k0, SRC);
        W.hN[ks] = wfrag(Whh, jA + 128, k0, SNC);
    }
    #pragma unroll
    for (int rg = 0; rg < 4; ++rg) {
        W.bR[rg]  = SRC * (bih[j4 + rg] + bhh[j4 + rg]);
        W.bZ[rg]  = SRC * (bih[64 + j4 + rg] + bhh[64 + j4 + rg]);
        W.bNi[rg] = SNC * bih[128 + j4 + rg];
        W.bNh[rg] = SNC * bhh[128 + j4 + rg];
    }
}
__device__ __forceinline__ void load_x_side(WSet& W, const float* __restrict__ Wx,
                                            int jA, int quad)
{
    #pragma unroll
    for (int ks = 0; ks < 2; ++ks) {
        const int k0 = ks * 32 + quad * 8;
        W.xR[ks] = wfrag(Wx, jA,       k0, SRC);
        W.xZ[ks] = wfrag(Wx, jA + 64,  k0, SRC);
        W.xN[ks] = wfrag(Wx, jA + 128, k0, SNC);
    }
}

// One GRU cell, D[j][row]. All LDS pointers are compile-time offsets of the
// shared block (call sites use literal buffer indices). Biases enter as the
// first MFMA's C operand.
template<bool XM>
__device__ __forceinline__ void cell(const WSet& W,
    const f16* __restrict__ Xs, const f16* __restrict__ Hs, f16* __restrict__ Dst,
    f16x4 (&ho)[4],
    const f32x4* __restrict__ xw, const float2* __restrict__ xv,
    int ro0, int ro1, int wo)
{
    #pragma unroll
    for (int mt = 0; mt < 4; ++mt) {
        const int mo = mt * 1024;
        f16x8 hb0 = *(const f16x8*)(Hs + ro0 + mo);
        f16x8 hb1 = *(const f16x8*)(Hs + ro1 + mo);
        f32x4 aR  = mfma16(W.hR[0], hb0, W.bR);
        f32x4 aZ  = mfma16(W.hZ[0], hb0, W.bZ);
        f32x4 aNh = mfma16(W.hN[0], hb0, W.bNh);
        aR  = mfma16(W.hR[1], hb1, aR);
        aZ  = mfma16(W.hZ[1], hb1, aZ);
        aNh = mfma16(W.hN[1], hb1, aNh);
        f32x4 aNi;
        if constexpr (XM) {
            f16x8 xb0 = *(const f16x8*)(Xs + ro0 + mo);
            f16x8 xb1 = *(const f16x8*)(Xs + ro1 + mo);
            aR  = mfma16(W.xR[0], xb0, aR);    aR  = mfma16(W.xR[1], xb1, aR);
            aZ  = mfma16(W.xZ[0], xb0, aZ);    aZ  = mfma16(W.xZ[1], xb1, aZ);
            aNi = mfma16(W.xN[0], xb0, W.bNi); aNi = mfma16(W.xN[1], xb1, aNi);
        } else {
            const float x0 = xv[mt].x, x1 = xv[mt].y;
            aR  += x0 * xw[0] + x1 * xw[1];
            aZ  += x0 * xw[2] + x1 * xw[3];
            aNi  = W.bNi + x0 * xw[4] + x1 * xw[5];
        }
        f16x4 o;
        #pragma unroll
        for (int i = 0; i < 4; ++i) {
            const float r = __builtin_amdgcn_rcpf(1.f + exp2r(aR[i]));
            const float z = __builtin_amdgcn_rcpf(1.f + exp2r(aZ[i]));
            const float n = 1.f - 2.f * __builtin_amdgcn_rcpf(1.f + exp2r(aNi[i] + r * aNh[i]));
            const float h = n + z * ((float)ho[mt][i] - n);
            o[i] = (f16)h;
        }
        ho[mt] = o;
        *(f16x4*)(Dst + wo + mo) = o;
    }
}

__global__ __launch_bounds__(256, 2)
void gru_traj_mfma8(
    const float* __restrict__ x,
    const float* __restrict__ eWih0, const float* __restrict__ eWhh0,
    const float* __restrict__ ebih0, const float* __restrict__ ebhh0,
    const float* __restrict__ eWih1, const float* __restrict__ eWhh1,
    const float* __restrict__ ebih1, const float* __restrict__ ebhh1,
    const float* __restrict__ dWih0, const float* __restrict__ dWhh0,
    const float* __restrict__ dbih0, const float* __restrict__ dbhh0,
    const float* __restrict__ dWih1, const float* __restrict__ dWhh1,
    const float* __restrict__ dbih1, const float* __restrict__ dbhh1,
    const float* __restrict__ fcW,  const float* __restrict__ fcb,
    float* __restrict__ out)
{
    // buffers: [0,1]=h0 double-buffer, [2,3]=h1 double-buffer, XOR-swizzled.
    __shared__ f16 hbuf[4][64 * 64];     // 32 KB
    __shared__ float2 xe[T_SEQ * 64];    // [t][row], 5.5 KB

    const int tid  = threadIdx.x;
    const int lane = tid & 63;
    const int w    = __builtin_amdgcn_readfirstlane(tid >> 6);
    const int quad = lane >> 4;
    const int col  = lane & 15;
    const int r0   = blockIdx.x * 64;

    // coalesced x staging: consecutive tid -> consecutive global float2
    {
        const float2* x2 = (const float2*)x;
        for (int i = tid; i < 64 * T_SEQ; i += 256) {
            const int row = i / T_SEQ, t = i - row * T_SEQ;
            xe[t * 64 + row] = x2[(size_t)r0 * T_SEQ + i];
        }
    }
    for (int i = tid; i < 64 * 64; i += 256) { hbuf[0][i] = (f16)0.f; hbuf[2][i] = (f16)0.f; }

    // Swizzle (halves): phys(row,k) = row*64 + (((k>>3)^(row&7))<<3) + (k&7)
    const int c7  = col & 7;
    const int ro0 = col * 64 + ((quad ^ c7) << 3);
    const int ro1 = col * 64 + (((4 + quad) ^ c7) << 3);
    const int wo  = col * 64 + ((((w << 1) | (quad >> 1)) ^ c7) << 3) + ((quad & 1) << 2);

    const int jA = w * 16 + col;
    const int j4 = w * 16 + quad * 4;

    f16x4 ho0[4], ho1[4];
    #pragma unroll
    for (int mt = 0; mt < 4; ++mt) {
        #pragma unroll
        for (int i = 0; i < 4; ++i) { ho0[mt][i] = (f16)0.f; ho1[mt][i] = (f16)0.f; }
    }

    WSet W0, W1;
    load_h_side(W0, eWhh0, ebih0, ebhh0, jA, j4, quad);
    load_h_side(W1, eWhh1, ebih1, ebhh1, jA, j4, quad);
    load_x_side(W1, eWih1, jA, quad);
    {
        f32x4 xw[6];
        #pragma unroll
        for (int rg = 0; rg < 4; ++rg) {
            xw[0][rg] = SRC * eWih0[(j4 + rg) * 2];        xw[1][rg] = SRC * eWih0[(j4 + rg) * 2 + 1];
            xw[2][rg] = SRC * eWih0[(64 + j4 + rg) * 2];   xw[3][rg] = SRC * eWih0[(64 + j4 + rg) * 2 + 1];
            xw[4][rg] = SNC * eWih0[(128 + j4 + rg) * 2];  xw[5][rg] = SNC * eWih0[(128 + j4 + rg) * 2 + 1];
        }
        __syncthreads();

        // ---------------- encoder: static buffers, 1 barrier/step ----------------
        #pragma unroll 1
        for (int t = 0; t < T_SEQ - 1; t += 2) {
            float2 xv[4];
            #pragma unroll
            for (int mt = 0; mt < 4; ++mt) xv[mt] = xe[t * 64 + mt * 16 + col];
            cell<false>(W0, hbuf[0], hbuf[0], hbuf[1], ho0, xw, xv, ro0, ro1, wo);
            __syncthreads();
            cell<true >(W1, hbuf[1], hbuf[2], hbuf[3], ho1, nullptr, nullptr, ro0, ro1, wo);
            #pragma unroll
            for (int mt = 0; mt < 4; ++mt) xv[mt] = xe[(t + 1) * 64 + mt * 16 + col];
            cell<false>(W0, hbuf[1], hbuf[1], hbuf[0], ho0, xw, xv, ro0, ro1, wo);
            __syncthreads();
            cell<true >(W1, hbuf[0], hbuf[3], hbuf[2], ho1, nullptr, nullptr, ro0, ro1, wo);
        }
        {   // t = 10 (even body)
            float2 xv[4];
            #pragma unroll
            for (int mt = 0; mt < 4; ++mt) xv[mt] = xe[10 * 64 + mt * 16 + col];
            cell<false>(W0, hbuf[0], hbuf[0], hbuf[1], ho0, xw, xv, ro0, ro1, wo);
            __syncthreads();
            cell<true >(W1, hbuf[1], hbuf[2], hbuf[3], ho1, nullptr, nullptr, ro0, ro1, wo);
        }
    }
    // now: h0 cur = hbuf[1], h1 cur = hbuf[3]

    // ---------------- phase switch ----------------
    load_h_side(W0, dWhh0, dbih0, dbhh0, jA, j4, quad);
    #pragma unroll
    for (int ks = 0; ks < 2; ++ks) {
        const int k0 = ks * 32 + quad * 8;
        W0.xR[ks] = cfrag(dWih0, fcW, jA,       k0, SRC);
        W0.xZ[ks] = cfrag(dWih0, fcW, jA + 64,  k0, SRC);
        W0.xN[ks] = cfrag(dWih0, fcW, jA + 128, k0, SNC);
    }
    #pragma unroll
    for (int rg = 0; rg < 4; ++rg) {   // fold fc_b through Wih0 (prescaled)
        const int j = j4 + rg;
        W0.bR[rg]  += SRC * (dWih0[j * 2] * fcb[0]         + dWih0[j * 2 + 1] * fcb[1]);
        W0.bZ[rg]  += SRC * (dWih0[(64 + j) * 2] * fcb[0]  + dWih0[(64 + j) * 2 + 1] * fcb[1]);
        W0.bNi[rg] += SNC * (dWih0[(128 + j) * 2] * fcb[0] + dWih0[(128 + j) * 2 + 1] * fcb[1]);
    }
    load_h_side(W1, dWhh1, dbih1, dbhh1, jA, j4, quad);
    load_x_side(W1, dWih1, jA, quad);
    f16x8 fcf[2];
    #pragma unroll
    for (int ks = 0; ks < 2; ++ks) {
        #pragma unroll
        for (int i = 0; i < 8; ++i) fcf[ks][i] = (f16)0.f;
        if (col < 2) fcf[ks] = wfrag(fcW, col, ks * 32 + quad * 8, 1.0f);
    }
    f32x4 pb;
    #pragma unroll
    for (int rg = 0; rg < 4; ++rg) pb[rg] = (quad == 0 && rg < 2) ? fcb[rg] : 0.f;

    float* __restrict__ op = out + (size_t)(r0 + w * 16 + col) * (STEPS * 2);

    // ---------------- decoder step 0 (peeled, x-path) ----------------
    {
        f32x4 xw[6];
        #pragma unroll
        for (int rg = 0; rg < 4; ++rg) {
            xw[0][rg] = SRC * dWih0[(j4 + rg) * 2];        xw[1][rg] = SRC * dWih0[(j4 + rg) * 2 + 1];
            xw[2][rg] = SRC * dWih0[(64 + j4 + rg) * 2];   xw[3][rg] = SRC * dWih0[(64 + j4 + rg) * 2 + 1];
            xw[4][rg] = SNC * dWih0[(128 + j4 + rg) * 2];  xw[5][rg] = SNC * dWih0[(128 + j4 + rg) * 2 + 1];
        }
        float2 xv0[4];
        #pragma unroll
        for (int mt = 0; mt < 4; ++mt) xv0[mt] = xe[10 * 64 + mt * 16 + col];
        cell<false>(W0, hbuf[1], hbuf[1], hbuf[0], ho0, xw, xv0, ro0, ro1, wo);
        __syncthreads();
        cell<true >(W1, hbuf[0], hbuf[3], hbuf[2], ho1, nullptr, nullptr, ro0, ro1, wo);
        __syncthreads();
        f16x8 hb0 = *(const f16x8*)(hbuf[2] + ro0 + w * 1024);
        f16x8 hb1 = *(const f16x8*)(hbuf[2] + ro1 + w * 1024);
        f32x4 p = mfma16(fcf[0], hb0, pb);
        p = mfma16(fcf[1], hb1, p);
        if (quad == 0) *(float2*)op = make_float2(p[0], p[1]);
        op += 2;
    }

    // ---------------- decoder: 39 pairs (odd, even) + 1 odd, static buffers ----
    #pragma unroll 1
    for (int sp = 0; sp < 39; ++sp) {
        cell<true>(W0, hbuf[2], hbuf[0], hbuf[1], ho0, nullptr, nullptr, ro0, ro1, wo);
        __syncthreads();
        cell<true>(W1, hbuf[1], hbuf[2], hbuf[3], ho1, nullptr, nullptr, ro0, ro1, wo);
        __syncthreads();
        {
            f16x8 hb0 = *(const f16x8*)(hbuf[3] + ro0 + w * 1024);
            f16x8 hb1 = *(const f16x8*)(hbuf[3] + ro1 + w * 1024);
            f32x4 p = mfma16(fcf[0], hb0, pb);
            p = mfma16(fcf[1], hb1, p);
            if (quad == 0) *(float2*)op = make_float2(p[0], p[1]);
            op += 2;
        }
        cell<true>(W0, hbuf[3], hbuf[1], hbuf[0], ho0, nullptr, nullptr, ro0, ro1, wo);
        __syncthreads();
        cell<true>(W1, hbuf[0], hbuf[3], hbuf[2], ho1, nullptr, nullptr, ro0, ro1, wo);
        __syncthreads();
        {
            f16x8 hb0 = *(const f16x8*)(hbuf[2] + ro0 + w * 1024);
            f16x8 hb1 = *(const f16x8*)(hbuf[2] + ro1 + w * 1024);
            f32x4 p = mfma16(fcf[0], hb0, pb);
            p = mfma16(fcf[1], hb1, p);
            if (quad == 0) *(float2*)op = make_float2(p[0], p[1]);
            op += 2;
        }
    }
    {   // s = 79 (odd body)
        cell<true>(W0, hbuf[2], hbuf[0], hbuf[1], ho0, nullptr, nullptr, ro0, ro1, wo);
        __syncthreads();
        cell<true>(W1, hbuf[1], hbuf[2], hbuf[3], ho1, nullptr, nullptr, ro0, ro1, wo);
        __syncthreads();
        f16x8 hb0 = *(const f16x8*)(hbuf[3] + ro0 + w * 1024);
        f16x8 hb1 = *(const f16x8*)(hbuf[3] + ro1 + w * 1024);
        f32x4 p = mfma16(fcf[0], hb0, pb);
        p = mfma16(fcf[1], hb1, p);
        if (quad == 0) *(float2*)op = make_float2(p[0], p[1]);
    }
}

extern "C" void kernel_launch(void* const* d_in, const int* in_sizes, int n_in,
                              void* d_out, int out_size, void* d_ws, size_t ws_size,
                              hipStream_t stream) {
    (void)n_in; (void)out_size; (void)d_ws; (void)ws_size;

    const float* x     = (const float*)d_in[0];
    const float* eWih0 = (const float*)d_in[1];
    const float* eWhh0 = (const float*)d_in[2];
    const float* ebih0 = (const float*)d_in[3];
    const float* ebhh0 = (const float*)d_in[4];
    const float* eWih1 = (const float*)d_in[5];
    const float* eWhh1 = (const float*)d_in[6];
    const float* ebih1 = (const float*)d_in[7];
    const float* ebhh1 = (const float*)d_in[8];
    const float* dWih0 = (const float*)d_in[9];
    const float* dWhh0 = (const float*)d_in[10];
    const float* dbih0 = (const float*)d_in[11];
    const float* dbhh0 = (const float*)d_in[12];
    const float* dWih1 = (const float*)d_in[13];
    const float* dWhh1 = (const float*)d_in[14];
    const float* dbih1 = (const float*)d_in[15];
    const float* dbhh1 = (const float*)d_in[16];
    const float* fcW   = (const float*)d_in[17];
    const float* fcb   = (const float*)d_in[18];
    float* out = (float*)d_out;

    const int b = in_sizes[0] / (T_SEQ * 2);   // 32768
    dim3 grid(b / 64), block(256);
    hipLaunchKernelGGL(gru_traj_mfma8, grid, block, 0, stream,
        x, eWih0, eWhh0, ebih0, ebhh0, eWih1, eWhh1, ebih1, ebhh1,
        dWih0, dWhh0, dbih0, dbhh0, dWih1, dWhh1, dbih1, dbhh1,
        fcW, fcb, out);
}